// Round 2
// baseline (908.867 us; speedup 1.0000x reference)
//
#include <hip/hip_runtime.h>
#include <math.h>

#define B_ 8
#define P_ 1024
#define N_ 32
#define L_ 125
#define H_ 256
#define E_ 128
#define BM 32
#define PAD 264   // 256 + 8: keeps rows 16B-aligned (264*4 = 1056 % 16 == 0)

static_assert(E_ == 3 + L_, "embed dim mismatch");

__constant__ float c_OUTPUT_BIAS = 0.5f;

// ---------------------------------------------------------------------------
// Kernel 1: Z[b][n][h] = b0[n][h] + sum_l latents[n][b][l] * W0[n][3+l][h]
// (the latent part of layer 0 does not depend on the point index p)
// ---------------------------------------------------------------------------
__global__ void z_precompute(const float* __restrict__ latents,
                             const float* __restrict__ W0,
                             const float* __restrict__ b0,
                             float* __restrict__ Z) {
  const int b = blockIdx.x;   // 0..B-1
  const int n = blockIdx.y;   // 0..N-1
  const int j = threadIdx.x;  // 0..H-1
  __shared__ float lat[L_];
  if (j < L_) lat[j] = latents[(n * B_ + b) * L_ + j];
  __syncthreads();
  const float* w0 = W0 + ((size_t)n * E_ + 3) * H_ + j;
  float acc = b0[n * H_ + j];
#pragma unroll 5
  for (int l = 0; l < L_; ++l)
    acc = fmaf(lat[l], w0[(size_t)l * H_], acc);
  Z[(b * N_ + n) * H_ + j] = acc;
}

// ---------------------------------------------------------------------------
// Main fused MLP kernel. Block = (point tile of 32, node n). 256 threads.
// Thread tile: TM=8 points x TN=4 cols; wave wv owns points wv*8..wv*8+7.
// ---------------------------------------------------------------------------
__device__ __forceinline__ void gemm_layer(const float (*__restrict__ bufIn)[PAD],
                                           const float* __restrict__ W,  // [H][H] + n offset
                                           int j0, int tbase,
                                           float acc[8][4]) {
#pragma unroll 2
  for (int k = 0; k < H_; k += 4) {
    const float* wp = W + (size_t)k * H_ + j0;
    const float4 q0 = *(const float4*)(wp);
    const float4 q1 = *(const float4*)(wp + H_);
    const float4 q2 = *(const float4*)(wp + 2 * H_);
    const float4 q3 = *(const float4*)(wp + 3 * H_);
    const float wa[4][4] = {{q0.x, q0.y, q0.z, q0.w},
                            {q1.x, q1.y, q1.z, q1.w},
                            {q2.x, q2.y, q2.z, q2.w},
                            {q3.x, q3.y, q3.z, q3.w}};
#pragma unroll
    for (int tt = 0; tt < 8; ++tt) {
      const float4 h4 = *(const float4*)(&bufIn[tbase + tt][k]);
      const float ha[4] = {h4.x, h4.y, h4.z, h4.w};
#pragma unroll
      for (int kk = 0; kk < 4; ++kk)
#pragma unroll
        for (int jj = 0; jj < 4; ++jj)
          acc[tt][jj] = fmaf(ha[kk], wa[kk][jj], acc[tt][jj]);
    }
  }
}

__global__ __launch_bounds__(256, 2)
void mlp_main(const float* __restrict__ X,
              const float* __restrict__ constants,
              const float* __restrict__ scales,
              const float* __restrict__ rotations,
              const float* __restrict__ centers,
              const float* __restrict__ W0,
              const float* __restrict__ W1,
              const float* __restrict__ b1,
              const float* __restrict__ W2,
              const float* __restrict__ b2,
              const float* __restrict__ Wout,
              const float* __restrict__ bout,
              const float* __restrict__ Z,
              const int* __restrict__ use_constants,
              float* __restrict__ accum) {
  __shared__ float buf0[BM][PAD];
  __shared__ float buf1[BM][PAD];
  __shared__ float loc[BM][3];
  __shared__ float wgt[BM];

  const int n = blockIdx.y;
  const int p0 = blockIdx.x * BM;     // global flattened point base (b*P + p)
  const int b = p0 >> 10;             // P_ == 1024
  const int tid = threadIdx.x;
  const int jg = tid & 63;            // lane within wave
  const int wv = tid >> 6;            // wave id 0..3
  const int j0 = jg * 4;              // this thread's 4 output columns
  const int tbase = wv * 8;           // this wave's 8 points

  // ---- per-point local coords + RBF weight (32 threads) ----
  if (tid < BM) {
    const int t = tid;
    const int pidx = p0 + t;
    const float x0 = X[pidx * 3 + 0];
    const float x1 = X[pidx * 3 + 1];
    const float x2 = X[pidx * 3 + 2];
    const float* R = rotations + (size_t)(b * N_ + n) * 9;
    const float* C = centers + (size_t)(b * N_ + n) * 3;
    const float* S = scales + (size_t)(b * N_ + n) * 3;
    const float d0 = x0 - C[0], d1 = x1 - C[1], d2 = x2 - C[2];
    const float l0 = (R[0] * d0 + R[1] * d1 + R[2] * d2) / S[0];
    const float l1 = (R[3] * d0 + R[4] * d1 + R[5] * d2) / S[1];
    const float l2 = (R[6] * d0 + R[7] * d1 + R[8] * d2) / S[2];
    loc[t][0] = l0;
    loc[t][1] = l1;
    loc[t][2] = l2;
    float w = expf(-0.5f * (l0 * l0 + l1 * l1 + l2 * l2));
    if (use_constants[0] != 0) w *= constants[b * N_ + n];
    wgt[t] = w;
  }
  __syncthreads();

  // ---- layer 0: h0 = relu(Z + local . W0[0:3]) ----
  {
    const float* w0 = W0 + (size_t)n * E_ * H_ + j0;
    const float4 z = *(const float4*)(Z + (size_t)(b * N_ + n) * H_ + j0);
    const float4 a0 = *(const float4*)(w0);
    const float4 a1 = *(const float4*)(w0 + H_);
    const float4 a2 = *(const float4*)(w0 + 2 * H_);
#pragma unroll
    for (int tt = 0; tt < 8; ++tt) {
      const int t = tbase + tt;
      const float l0 = loc[t][0], l1 = loc[t][1], l2 = loc[t][2];
      float4 h;
      h.x = fmaf(l2, a2.x, fmaf(l1, a1.x, fmaf(l0, a0.x, z.x)));
      h.y = fmaf(l2, a2.y, fmaf(l1, a1.y, fmaf(l0, a0.y, z.y)));
      h.z = fmaf(l2, a2.z, fmaf(l1, a1.z, fmaf(l0, a0.z, z.z)));
      h.w = fmaf(l2, a2.w, fmaf(l1, a1.w, fmaf(l0, a0.w, z.w)));
      h.x = fmaxf(h.x, 0.f);
      h.y = fmaxf(h.y, 0.f);
      h.z = fmaxf(h.z, 0.f);
      h.w = fmaxf(h.w, 0.f);
      *(float4*)(&buf0[t][j0]) = h;
    }
  }
  __syncthreads();

  // ---- layer 1 ----
  float acc[8][4];
#pragma unroll
  for (int tt = 0; tt < 8; ++tt)
#pragma unroll
    for (int jj = 0; jj < 4; ++jj) acc[tt][jj] = 0.f;

  gemm_layer(buf0, W1 + (size_t)n * H_ * H_, j0, tbase, acc);
  {
    const float4 bb = *(const float4*)(b1 + n * H_ + j0);
#pragma unroll
    for (int tt = 0; tt < 8; ++tt) {
      float4 h;
      h.x = fmaxf(acc[tt][0] + bb.x, 0.f);
      h.y = fmaxf(acc[tt][1] + bb.y, 0.f);
      h.z = fmaxf(acc[tt][2] + bb.z, 0.f);
      h.w = fmaxf(acc[tt][3] + bb.w, 0.f);
      *(float4*)(&buf1[tbase + tt][j0]) = h;
    }
  }
  __syncthreads();

  // ---- layer 2 (+ fused Wout dot) ----
#pragma unroll
  for (int tt = 0; tt < 8; ++tt)
#pragma unroll
    for (int jj = 0; jj < 4; ++jj) acc[tt][jj] = 0.f;

  gemm_layer(buf1, W2 + (size_t)n * H_ * H_, j0, tbase, acc);

  const float4 bb2 = *(const float4*)(b2 + n * H_ + j0);
  const float4 wo = *(const float4*)(Wout + n * H_ + j0);
  float pred[8];
#pragma unroll
  for (int tt = 0; tt < 8; ++tt) {
    const float h0 = fmaxf(acc[tt][0] + bb2.x, 0.f);
    const float h1 = fmaxf(acc[tt][1] + bb2.y, 0.f);
    const float h2 = fmaxf(acc[tt][2] + bb2.z, 0.f);
    const float h3 = fmaxf(acc[tt][3] + bb2.w, 0.f);
    pred[tt] = fmaf(h0, wo.x, fmaf(h1, wo.y, fmaf(h2, wo.z, h3 * wo.w)));
  }
  // reduce across the 64 lanes of this wave (cols 0..255)
#pragma unroll
  for (int off = 1; off < 64; off <<= 1) {
#pragma unroll
    for (int tt = 0; tt < 8; ++tt) pred[tt] += __shfl_xor(pred[tt], off, 64);
  }
  if (jg == 0) {
    const float bo = bout[n] + c_OUTPUT_BIAS;
#pragma unroll
    for (int tt = 0; tt < 8; ++tt) {
      const int t = tbase + tt;
      atomicAdd(&accum[p0 + t], wgt[t] * (pred[tt] + bo));
    }
  }
}

// ---------------------------------------------------------------------------
// Kernel 3: finalize — copy ldif, apply inverse-occupancy sigmoid
// ---------------------------------------------------------------------------
__global__ void finalize(const float* __restrict__ accum, float* __restrict__ out) {
  const int i = blockIdx.x * 256 + threadIdx.x;
  const float v = accum[i];
  out[i] = v;
  const float zz = 100.0f * (-0.07f - v);
  out[B_ * P_ + i] = 1.0f / (1.0f + expf(-zz));
}

// ---------------------------------------------------------------------------
extern "C" void kernel_launch(void* const* d_in, const int* in_sizes, int n_in,
                              void* d_out, int out_size, void* d_ws, size_t ws_size,
                              hipStream_t stream) {
  const float* X = (const float*)d_in[0];
  const float* latents = (const float*)d_in[1];
  const float* constants = (const float*)d_in[2];
  const float* scales = (const float*)d_in[3];
  const float* rotations = (const float*)d_in[4];
  const float* centers = (const float*)d_in[5];
  const float* W0 = (const float*)d_in[6];
  const float* b0 = (const float*)d_in[7];
  const float* W1 = (const float*)d_in[8];
  const float* b1 = (const float*)d_in[9];
  const float* W2 = (const float*)d_in[10];
  const float* b2 = (const float*)d_in[11];
  const float* Wout = (const float*)d_in[12];
  const float* bout = (const float*)d_in[13];
  const int* use_constants = (const int*)d_in[14];

  float* accum = (float*)d_ws;             // B*P floats (32 KB)
  float* Z = (float*)d_ws + B_ * P_;       // B*N*H floats (256 KB)

  hipMemsetAsync(accum, 0, B_ * P_ * sizeof(float), stream);

  z_precompute<<<dim3(B_, N_), 256, 0, stream>>>(latents, W0, b0, Z);

  mlp_main<<<dim3(B_ * P_ / BM, N_), 256, 0, stream>>>(
      X, constants, scales, rotations, centers, W0, W1, b1, W2, b2, Wout, bout,
      Z, use_constants, accum);

  finalize<<<dim3(B_ * P_ / 256), 256, 0, stream>>>(accum, (float*)d_out);
}

// Round 5
// 399.052 us; speedup vs baseline: 2.2776x; 2.2776x over previous
//
#include <hip/hip_runtime.h>
#include <math.h>

#define B_ 8
#define P_ 1024
#define N_ 32
#define L_ 125
#define H_ 256
#define E_ 128
#define MT 128            // points per block (8 waves x 16 m-cols... see mapping)
#define NW 8

static_assert(E_ == 3 + L_, "embed dim mismatch");

typedef _Float16 half8 __attribute__((ext_vector_type(8)));
typedef _Float16 half4v __attribute__((ext_vector_type(4)));
typedef float f32x4 __attribute__((ext_vector_type(4)));

// ---------------------------------------------------------------------------
// Z[b][n][j] = b0[n][j] + sum_l latents[n][b][l] * W0[n][3+l][j]
// ---------------------------------------------------------------------------
__global__ void z_precompute(const float* __restrict__ latents,
                             const float* __restrict__ W0,
                             const float* __restrict__ b0,
                             float* __restrict__ Z) {
  const int b = blockIdx.x;
  const int n = blockIdx.y;
  const int j = threadIdx.x;
  __shared__ float lat[L_];
  if (j < L_) lat[j] = latents[(n * B_ + b) * L_ + j];
  __syncthreads();
  const float* w0 = W0 + ((size_t)n * E_ + 3) * H_ + j;
  float acc = b0[n * H_ + j];
#pragma unroll 5
  for (int l = 0; l < L_; ++l)
    acc = fmaf(lat[l], w0[(size_t)l * H_], acc);
  Z[(b * N_ + n) * H_ + j] = acc;
}

// ---------------------------------------------------------------------------
// Transpose + hi/lo f16 split of W1,W2:  WT[layer][node][j_out][h_in]
// ---------------------------------------------------------------------------
__global__ void wsplit(const float* __restrict__ W1, const float* __restrict__ W2,
                       _Float16* __restrict__ WThi, _Float16* __restrict__ WTlo) {
  const int node = blockIdx.x;
  const int layer = blockIdx.y;
  const float* W = (layer == 0 ? W1 : W2) + (size_t)node * H_ * H_;
  _Float16* dhi = WThi + ((size_t)layer * N_ + node) * H_ * H_;
  _Float16* dlo = WTlo + ((size_t)layer * N_ + node) * H_ * H_;
  __shared__ float tile[64][65];
  const int t = threadIdx.x;
  for (int hb = 0; hb < 4; ++hb)
    for (int jb = 0; jb < 4; ++jb) {
#pragma unroll
      for (int i = 0; i < 16; ++i) {
        const int row = (t >> 6) + 4 * i;
        const int col = t & 63;
        tile[row][col] = W[(size_t)(hb * 64 + row) * H_ + jb * 64 + col];
      }
      __syncthreads();
      {
        const int j_l = t >> 2;
        const int h0 = (t & 3) * 16;
        half8 hv0, hv1, lv0, lv1;
#pragma unroll
        for (int q = 0; q < 16; ++q) {
          const float v = tile[h0 + q][j_l];
          const _Float16 hh = (_Float16)v;
          const _Float16 ll = (_Float16)(v - (float)hh);
          if (q < 8) { hv0[q] = hh; lv0[q] = ll; }
          else       { hv1[q - 8] = hh; lv1[q - 8] = ll; }
        }
        const size_t off = (size_t)(jb * 64 + j_l) * H_ + hb * 64 + h0;
        *(half8*)(dhi + off) = hv0;
        *(half8*)(dhi + off + 8) = hv1;
        *(half8*)(dlo + off) = lv0;
        *(half8*)(dlo + off + 8) = lv1;
      }
      __syncthreads();
    }
}

// ---------------------------------------------------------------------------
// Main fused kernel: block = (128-point tile, node). 512 threads = 8 waves.
// Computes C^T = W^T * h^T per layer with 3-term split-f16 MFMA.
// Wave w owns output-neuron rows [32w, 32w+32); LDS h buffer shared.
// ---------------------------------------------------------------------------
__global__ __launch_bounds__(512, 2)
void mlp_main(const float* __restrict__ X,
              const float* __restrict__ constants,
              const float* __restrict__ scales,
              const float* __restrict__ rotations,
              const float* __restrict__ centers,
              const float* __restrict__ W0,
              const float* __restrict__ b1,
              const float* __restrict__ b2,
              const float* __restrict__ Wout,
              const float* __restrict__ bout,
              const float* __restrict__ Z,
              const _Float16* __restrict__ WThi,
              const _Float16* __restrict__ WTlo,
              const int* __restrict__ use_constants,
              float* __restrict__ accum) {
  __shared__ _Float16 h_hi[MT * H_];   // 64 KB
  __shared__ _Float16 h_lo[MT * H_];   // 64 KB
  __shared__ float loc[MT][3];
  __shared__ float wgt[MT];
  __shared__ float predpart[MT];

  const int node = blockIdx.y;
  const int p0 = blockIdx.x * MT;
  const int b = p0 >> 10;
  const int tid = threadIdx.x;
  const int lane = tid & 63;
  const int w = tid >> 6;
  const int c = lane & 15;     // MFMA "col" index (point dir for C^T)
  const int g = lane >> 4;     // MFMA k-group

  if (tid < MT) {
    predpart[tid] = 0.f;
    const int t = tid;
    const int pidx = p0 + t;
    const float x0 = X[pidx * 3 + 0];
    const float x1 = X[pidx * 3 + 1];
    const float x2 = X[pidx * 3 + 2];
    const float* R = rotations + (size_t)(b * N_ + node) * 9;
    const float* C = centers + (size_t)(b * N_ + node) * 3;
    const float* S = scales + (size_t)(b * N_ + node) * 3;
    const float d0 = x0 - C[0], d1 = x1 - C[1], d2 = x2 - C[2];
    const float l0 = (R[0] * d0 + R[1] * d1 + R[2] * d2) / S[0];
    const float l1 = (R[3] * d0 + R[4] * d1 + R[5] * d2) / S[1];
    const float l2 = (R[6] * d0 + R[7] * d1 + R[8] * d2) / S[2];
    loc[t][0] = l0; loc[t][1] = l1; loc[t][2] = l2;
    float ww = expf(-0.5f * (l0 * l0 + l1 * l1 + l2 * l2));
    if (use_constants[0] != 0) ww *= constants[b * N_ + node];
    wgt[t] = ww;
  }
  __syncthreads();

  // ---- layer 0: h0[m][j] = relu(Z[j] + local[m] . W0[0:3][j]), split to LDS
  {
    const int m = tid & 127;
    const int n0 = (tid >> 7) * 64;
    const float l0 = loc[m][0], l1 = loc[m][1], l2 = loc[m][2];
    const float* w0p = W0 + (size_t)node * E_ * H_;
    const float* zp = Z + (size_t)(b * N_ + node) * H_;
#pragma unroll 4
    for (int j = 0; j < 64; j += 4) {
      const float4 a0 = *(const float4*)(w0p + n0 + j);
      const float4 a1 = *(const float4*)(w0p + H_ + n0 + j);
      const float4 a2 = *(const float4*)(w0p + 2 * H_ + n0 + j);
      const float4 zz = *(const float4*)(zp + n0 + j);
      float v[4];
      v[0] = fmaxf(fmaf(l0, a0.x, fmaf(l1, a1.x, fmaf(l2, a2.x, zz.x))), 0.f);
      v[1] = fmaxf(fmaf(l0, a0.y, fmaf(l1, a1.y, fmaf(l2, a2.y, zz.y))), 0.f);
      v[2] = fmaxf(fmaf(l0, a0.z, fmaf(l1, a1.z, fmaf(l2, a2.z, zz.z))), 0.f);
      v[3] = fmaxf(fmaf(l0, a0.w, fmaf(l1, a1.w, fmaf(l2, a2.w, zz.w))), 0.f);
      half4v hv, lv;
#pragma unroll
      for (int r = 0; r < 4; ++r) {
        const _Float16 hh = (_Float16)v[r];
        hv[r] = hh;
        lv[r] = (_Float16)(v[r] - (float)hh);
      }
      const int sidx = ((m << 8) + n0 + j) ^ ((m & 7) << 3);
      *(half4v*)(&h_hi[sidx]) = hv;
      *(half4v*)(&h_lo[sidx]) = lv;
    }
  }
  __syncthreads();

  f32x4 acc[2][8];   // [nt: 16-row j-tile][mt: 16-col m-tile]

  const _Float16* wt1hi = WThi + (size_t)node * H_ * H_;
  const _Float16* wt1lo = WTlo + (size_t)node * H_ * H_;
  const _Float16* wt2hi = WThi + ((size_t)N_ + node) * H_ * H_;
  const _Float16* wt2lo = WTlo + ((size_t)N_ + node) * H_ * H_;

  auto run_layer = [&](const _Float16* whi, const _Float16* wlo) {
#pragma unroll
    for (int nt = 0; nt < 2; ++nt)
#pragma unroll
      for (int mt = 0; mt < 8; ++mt) acc[nt][mt] = (f32x4)(0.f);
#pragma unroll
    for (int kc = 0; kc < 8; ++kc) {
      half8 ah[2], al[2];
#pragma unroll
      for (int nt = 0; nt < 2; ++nt) {
        const size_t aoff = ((size_t)(32 * w + 16 * nt + c) << 8) + (kc << 5) + (g << 3);
        ah[nt] = *(const half8*)(whi + aoff);
        al[nt] = *(const half8*)(wlo + aoff);
      }
#pragma unroll
      for (int mt = 0; mt < 8; ++mt) {
        const int m = c + 16 * mt;
        const int sidx = (((m << 8) + (kc << 5) + (g << 3))) ^ ((m & 7) << 3);
        const half8 bh = *(const half8*)(&h_hi[sidx]);
        const half8 bl = *(const half8*)(&h_lo[sidx]);
#pragma unroll
        for (int nt = 0; nt < 2; ++nt) {
          acc[nt][mt] = __builtin_amdgcn_mfma_f32_16x16x32_f16(ah[nt], bh, acc[nt][mt], 0, 0, 0);
          acc[nt][mt] = __builtin_amdgcn_mfma_f32_16x16x32_f16(ah[nt], bl, acc[nt][mt], 0, 0, 0);
          acc[nt][mt] = __builtin_amdgcn_mfma_f32_16x16x32_f16(al[nt], bh, acc[nt][mt], 0, 0, 0);
        }
      }
    }
  };

  // ---- layer 1 ----
  run_layer(wt1hi, wt1lo);
  __syncthreads();   // all reads of h_buf complete
  {
#pragma unroll
    for (int nt = 0; nt < 2; ++nt) {
      const int jb = 32 * w + 16 * nt + 4 * g;
      const float4 bb = *(const float4*)(b1 + node * H_ + jb);
      const float bv[4] = {bb.x, bb.y, bb.z, bb.w};
#pragma unroll
      for (int mt = 0; mt < 8; ++mt) {
        const int m = c + 16 * mt;
        half4v hv, lv;
#pragma unroll
        for (int r = 0; r < 4; ++r) {
          const float v = fmaxf(acc[nt][mt][r] + bv[r], 0.f);
          const _Float16 hh = (_Float16)v;
          hv[r] = hh;
          lv[r] = (_Float16)(v - (float)hh);
        }
        const int sidx = ((m << 8) + jb) ^ ((m & 7) << 3);
        *(half4v*)(&h_hi[sidx]) = hv;
        *(half4v*)(&h_lo[sidx]) = lv;
      }
    }
  }
  __syncthreads();

  // ---- layer 2 + fused Wout ----
  run_layer(wt2hi, wt2lo);
  {
    float s[8];
#pragma unroll
    for (int mt = 0; mt < 8; ++mt) s[mt] = 0.f;
#pragma unroll
    for (int nt = 0; nt < 2; ++nt) {
      const int jb = 32 * w + 16 * nt + 4 * g;
      const float4 bb = *(const float4*)(b2 + node * H_ + jb);
      const float4 wo = *(const float4*)(Wout + node * H_ + jb);
      const float bv[4] = {bb.x, bb.y, bb.z, bb.w};
      const float wv[4] = {wo.x, wo.y, wo.z, wo.w};
#pragma unroll
      for (int mt = 0; mt < 8; ++mt) {
#pragma unroll
        for (int r = 0; r < 4; ++r)
          s[mt] = fmaf(fmaxf(acc[nt][mt][r] + bv[r], 0.f), wv[r], s[mt]);
      }
    }
#pragma unroll
    for (int mt = 0; mt < 8; ++mt) {
      s[mt] += __shfl_xor(s[mt], 16, 64);
      s[mt] += __shfl_xor(s[mt], 32, 64);
    }
    if (g == 0) {
#pragma unroll
      for (int mt = 0; mt < 8; ++mt)
        atomicAdd(&predpart[c + 16 * mt], s[mt]);
    }
  }
  __syncthreads();

  if (tid < MT) {
    const float pr = predpart[tid] + bout[node] + 0.5f;
    atomicAdd(&accum[p0 + tid], wgt[tid] * pr);
  }
}

// ---------------------------------------------------------------------------
__global__ void finalize(const float* __restrict__ accum, float* __restrict__ out) {
  const int i = blockIdx.x * 256 + threadIdx.x;
  const float v = accum[i];
  out[i] = v;
  const float zz = 100.0f * (-0.07f - v);
  out[B_ * P_ + i] = 1.0f / (1.0f + expf(-zz));
}

// ---------------------------------------------------------------------------
extern "C" void kernel_launch(void* const* d_in, const int* in_sizes, int n_in,
                              void* d_out, int out_size, void* d_ws, size_t ws_size,
                              hipStream_t stream) {
  const float* X = (const float*)d_in[0];
  const float* latents = (const float*)d_in[1];
  const float* constants = (const float*)d_in[2];
  const float* scales = (const float*)d_in[3];
  const float* rotations = (const float*)d_in[4];
  const float* centers = (const float*)d_in[5];
  const float* W0 = (const float*)d_in[6];
  const float* b0 = (const float*)d_in[7];
  const float* W1 = (const float*)d_in[8];
  const float* b1 = (const float*)d_in[9];
  const float* W2 = (const float*)d_in[10];
  const float* b2 = (const float*)d_in[11];
  const float* Wout = (const float*)d_in[12];
  const float* bout = (const float*)d_in[13];
  const int* use_constants = (const int*)d_in[14];

  float* accum = (float*)d_ws;                       // 8192 f32
  float* Zbuf = accum + B_ * P_;                     // 65536 f32
  _Float16* WThi = (_Float16*)(Zbuf + B_ * N_ * H_); // 2*32*65536 halves (8 MB)
  _Float16* WTlo = WThi + (size_t)2 * N_ * H_ * H_;  // 8 MB

  hipMemsetAsync(accum, 0, B_ * P_ * sizeof(float), stream);

  z_precompute<<<dim3(B_, N_), 256, 0, stream>>>(latents, W0, b0, Zbuf);
  wsplit<<<dim3(N_, 2), 256, 0, stream>>>(W1, W2, WThi, WTlo);

  mlp_main<<<dim3(B_ * P_ / MT, N_), 512, 0, stream>>>(
      X, constants, scales, rotations, centers, W0, b1, b2, Wout, bout,
      Zbuf, WThi, WTlo, use_constants, accum);

  finalize<<<dim3(B_ * P_ / 256), 256, 0, stream>>>(accum, (float*)d_out);
}

// Round 7
// 366.347 us; speedup vs baseline: 2.4809x; 1.0893x over previous
//
#include <hip/hip_runtime.h>
#include <math.h>

#define B_ 8
#define P_ 1024
#define N_ 32
#define L_ 125
#define H_ 256
#define E_ 128
#define MT 64             // points per block (8 waves; wave w owns j-rows 32w..32w+32)

static_assert(E_ == 3 + L_, "embed dim mismatch");

typedef _Float16 half8 __attribute__((ext_vector_type(8)));
typedef _Float16 half4v __attribute__((ext_vector_type(4)));
typedef float f32x4 __attribute__((ext_vector_type(4)));

// ---------------------------------------------------------------------------
// Z[b][n][j] += b0 (zs==0) + sum over this block's l-range of lat*W0.
// 4-way K-split over l: 1024 blocks instead of 256 (was a 125-deep chain).
// Z must be zeroed before launch (memset in kernel_launch).
// ---------------------------------------------------------------------------
__global__ void z_precompute(const float* __restrict__ latents,
                             const float* __restrict__ W0,
                             const float* __restrict__ b0,
                             float* __restrict__ Z) {
  const int b = blockIdx.x;
  const int n = blockIdx.y;
  const int zs = blockIdx.z;            // 0..3, l-range [32*zs, min(32*zs+32,125))
  const int j = threadIdx.x;
  const int l0 = zs * 32;
  const int nl = (l0 + 32 <= L_) ? 32 : (L_ - l0);
  __shared__ float lat[32];
  if (j < nl) lat[j] = latents[(n * B_ + b) * L_ + l0 + j];
  __syncthreads();
  const float* w0 = W0 + ((size_t)n * E_ + 3 + l0) * H_ + j;
  float acc = (zs == 0) ? b0[n * H_ + j] : 0.f;
  for (int l = 0; l < nl; ++l)
    acc = fmaf(lat[l], w0[(size_t)l * H_], acc);
  atomicAdd(&Z[(b * N_ + n) * H_ + j], acc);
}

// ---------------------------------------------------------------------------
// Transpose + hi/lo f16 split of W1,W2: WT[layer][node][j_out][h_in].
// Parallelized over (node, layer, jb-quarter) = 256 blocks (was 64).
// ---------------------------------------------------------------------------
__global__ void wsplit(const float* __restrict__ W1, const float* __restrict__ W2,
                       _Float16* __restrict__ WThi, _Float16* __restrict__ WTlo) {
  const int node = blockIdx.x;
  const int layer = blockIdx.y;
  const int jb = blockIdx.z;            // 0..3: 64-wide j slice
  const float* W = (layer == 0 ? W1 : W2) + (size_t)node * H_ * H_;
  _Float16* dhi = WThi + ((size_t)layer * N_ + node) * H_ * H_;
  _Float16* dlo = WTlo + ((size_t)layer * N_ + node) * H_ * H_;
  __shared__ float tile[64][65];
  const int t = threadIdx.x;
  for (int hb = 0; hb < 4; ++hb) {
#pragma unroll
    for (int i = 0; i < 16; ++i) {
      const int row = (t >> 6) + 4 * i;
      const int col = t & 63;
      tile[row][col] = W[(size_t)(hb * 64 + row) * H_ + jb * 64 + col];
    }
    __syncthreads();
    {
      const int j_l = t >> 2;           // 0..63
      const int h0 = (t & 3) * 16;      // 0,16,32,48
      half8 hv0, hv1, lv0, lv1;
#pragma unroll
      for (int q = 0; q < 16; ++q) {
        const float v = tile[h0 + q][j_l];
        const _Float16 hh = (_Float16)v;
        const _Float16 ll = (_Float16)(v - (float)hh);
        if (q < 8) { hv0[q] = hh; lv0[q] = ll; }
        else       { hv1[q - 8] = hh; lv1[q - 8] = ll; }
      }
      const size_t off = (size_t)(jb * 64 + j_l) * H_ + hb * 64 + h0;
      *(half8*)(dhi + off) = hv0;
      *(half8*)(dhi + off + 8) = hv1;
      *(half8*)(dlo + off) = lv0;
      *(half8*)(dlo + off + 8) = lv1;
    }
    __syncthreads();
  }
}

// ---------------------------------------------------------------------------
// Main fused kernel. Flat grid of 4096 blocks; block decodes (node, ptile)
// with an XCD-aware swizzle so each XCD's L2 holds only 4 nodes' weights
// (~2 MB < 4 MB per-XCD L2). Block = 64 points x 1 node, 512 thr = 8 waves.
// C^T = W^T * h^T per layer, 3-term split-f16 MFMA (hh + hl + lh).
// LDS 65 KB -> 2 blocks/CU (16 waves/CU, 4/SIMD).
// ---------------------------------------------------------------------------
__global__ __launch_bounds__(512, 4)
void mlp_main(const float* __restrict__ X,
              const float* __restrict__ constants,
              const float* __restrict__ scales,
              const float* __restrict__ rotations,
              const float* __restrict__ centers,
              const float* __restrict__ W0,
              const float* __restrict__ b1,
              const float* __restrict__ b2,
              const float* __restrict__ Wout,
              const float* __restrict__ bout,
              const float* __restrict__ Z,
              const _Float16* __restrict__ WThi,
              const _Float16* __restrict__ WTlo,
              const int* __restrict__ use_constants,
              float* __restrict__ accum) {
  __shared__ _Float16 h_hi[MT * H_];   // 32 KB
  __shared__ _Float16 h_lo[MT * H_];   // 32 KB
  __shared__ float loc[MT][3];
  __shared__ float wgt[MT];
  __shared__ float predpart[MT];

  // XCD swizzle: linear block id ell; assumed xcd = ell % 8. node = xcd*4 + q
  // so each XCD sees only 4 distinct nodes across the whole dispatch.
  const int ell = blockIdx.x;
  const int node = (ell & 7) * 4 + ((ell >> 3) & 3);
  const int p0 = (ell >> 5) * MT;       // point-tile base (b*P + p)
  const int b = p0 >> 10;               // P_ == 1024
  const int tid = threadIdx.x;
  const int lane = tid & 63;
  const int w = tid >> 6;
  const int c = lane & 15;              // MFMA col index (point dir for C^T)
  const int g = lane >> 4;              // MFMA k-group

  if (tid < MT) {
    predpart[tid] = 0.f;
    const int t = tid;
    const int pidx = p0 + t;
    const float x0 = X[pidx * 3 + 0];
    const float x1 = X[pidx * 3 + 1];
    const float x2 = X[pidx * 3 + 2];
    const float* R = rotations + (size_t)(b * N_ + node) * 9;
    const float* C = centers + (size_t)(b * N_ + node) * 3;
    const float* S = scales + (size_t)(b * N_ + node) * 3;
    const float d0 = x0 - C[0], d1 = x1 - C[1], d2 = x2 - C[2];
    const float l0 = (R[0] * d0 + R[1] * d1 + R[2] * d2) / S[0];
    const float l1 = (R[3] * d0 + R[4] * d1 + R[5] * d2) / S[1];
    const float l2 = (R[6] * d0 + R[7] * d1 + R[8] * d2) / S[2];
    loc[t][0] = l0; loc[t][1] = l1; loc[t][2] = l2;
    float ww = expf(-0.5f * (l0 * l0 + l1 * l1 + l2 * l2));
    if (use_constants[0] != 0) ww *= constants[b * N_ + node];
    wgt[t] = ww;
  }
  __syncthreads();

  // ---- layer 0: wave-per-row writes (row-contiguous b64 -> conflict-free).
  // Each lane owns 4 j-columns; W0/Z loads hoisted out of the m loop.
  {
    const int j0 = lane * 4;
    const float* w0p = W0 + (size_t)node * E_ * H_;
    const float4 a0 = *(const float4*)(w0p + j0);
    const float4 a1 = *(const float4*)(w0p + H_ + j0);
    const float4 a2 = *(const float4*)(w0p + 2 * H_ + j0);
    const float4 zz = *(const float4*)(Z + (size_t)(b * N_ + node) * H_ + j0);
#pragma unroll
    for (int i = 0; i < 8; ++i) {
      const int m = w * 8 + i;
      const float l0 = loc[m][0], l1 = loc[m][1], l2 = loc[m][2];
      float v[4];
      v[0] = fmaxf(fmaf(l2, a2.x, fmaf(l1, a1.x, fmaf(l0, a0.x, zz.x))), 0.f);
      v[1] = fmaxf(fmaf(l2, a2.y, fmaf(l1, a1.y, fmaf(l0, a0.y, zz.y))), 0.f);
      v[2] = fmaxf(fmaf(l2, a2.z, fmaf(l1, a1.z, fmaf(l0, a0.z, zz.z))), 0.f);
      v[3] = fmaxf(fmaf(l2, a2.w, fmaf(l1, a1.w, fmaf(l0, a0.w, zz.w))), 0.f);
      half4v hv, lv;
#pragma unroll
      for (int r = 0; r < 4; ++r) {
        const _Float16 hh = (_Float16)v[r];
        hv[r] = hh;
        lv[r] = (_Float16)(v[r] - (float)hh);
      }
      const int sidx = ((m << 8) + j0) ^ ((m & 7) << 3);
      *(half4v*)(&h_hi[sidx]) = hv;
      *(half4v*)(&h_lo[sidx]) = lv;
    }
  }
  __syncthreads();

  f32x4 acc[2][4];   // [nt: 16-row j-tile][mt: 16-col m-tile]

  const _Float16* wt1hi = WThi + (size_t)node * H_ * H_;
  const _Float16* wt1lo = WTlo + (size_t)node * H_ * H_;
  const _Float16* wt2hi = WThi + ((size_t)N_ + node) * H_ * H_;
  const _Float16* wt2lo = WTlo + ((size_t)N_ + node) * H_ * H_;

  auto run_layer = [&](const _Float16* whi, const _Float16* wlo) {
#pragma unroll
    for (int nt = 0; nt < 2; ++nt)
#pragma unroll
      for (int mt = 0; mt < 4; ++mt) acc[nt][mt] = (f32x4)(0.f);
#pragma unroll
    for (int kc = 0; kc < 8; ++kc) {
      half8 ah[2], al[2];
#pragma unroll
      for (int nt = 0; nt < 2; ++nt) {
        const size_t aoff = ((size_t)(32 * w + 16 * nt + c) << 8) + (kc << 5) + (g << 3);
        ah[nt] = *(const half8*)(whi + aoff);
        al[nt] = *(const half8*)(wlo + aoff);
      }
#pragma unroll
      for (int mt = 0; mt < 4; ++mt) {
        const int m = c + 16 * mt;
        const int sidx = (((m << 8) + (kc << 5) + (g << 3))) ^ ((m & 7) << 3);
        const half8 bh = *(const half8*)(&h_hi[sidx]);
        const half8 bl = *(const half8*)(&h_lo[sidx]);
#pragma unroll
        for (int nt = 0; nt < 2; ++nt) {
          acc[nt][mt] = __builtin_amdgcn_mfma_f32_16x16x32_f16(ah[nt], bh, acc[nt][mt], 0, 0, 0);
          acc[nt][mt] = __builtin_amdgcn_mfma_f32_16x16x32_f16(ah[nt], bl, acc[nt][mt], 0, 0, 0);
          acc[nt][mt] = __builtin_amdgcn_mfma_f32_16x16x32_f16(al[nt], bh, acc[nt][mt], 0, 0, 0);
        }
      }
    }
  };

  // ---- layer 1 ----
  run_layer(wt1hi, wt1lo);
  __syncthreads();   // all reads of h bufs complete before overwrite
  {
#pragma unroll
    for (int nt = 0; nt < 2; ++nt) {
      const int jb = 32 * w + 16 * nt + 4 * g;
      const float4 bb = *(const float4*)(b1 + node * H_ + jb);
      const float bv[4] = {bb.x, bb.y, bb.z, bb.w};
#pragma unroll
      for (int mt = 0; mt < 4; ++mt) {
        const int m = c + 16 * mt;
        half4v hv, lv;
#pragma unroll
        for (int r = 0; r < 4; ++r) {
          const float v = fmaxf(acc[nt][mt][r] + bv[r], 0.f);
          const _Float16 hh = (_Float16)v;
          hv[r] = hh;
          lv[r] = (_Float16)(v - (float)hh);
        }
        const int sidx = ((m << 8) + jb) ^ ((m & 7) << 3);
        *(half4v*)(&h_hi[sidx]) = hv;
        *(half4v*)(&h_lo[sidx]) = lv;
      }
    }
  }
  __syncthreads();

  // ---- layer 2 + fused Wout ----
  run_layer(wt2hi, wt2lo);
  {
    float s[4];
#pragma unroll
    for (int mt = 0; mt < 4; ++mt) s[mt] = 0.f;
#pragma unroll
    for (int nt = 0; nt < 2; ++nt) {
      const int jb = 32 * w + 16 * nt + 4 * g;
      const float4 bb = *(const float4*)(b2 + node * H_ + jb);
      const float4 wo = *(const float4*)(Wout + node * H_ + jb);
      const float bv[4] = {bb.x, bb.y, bb.z, bb.w};
      const float wv[4] = {wo.x, wo.y, wo.z, wo.w};
#pragma unroll
      for (int mt = 0; mt < 4; ++mt) {
#pragma unroll
        for (int r = 0; r < 4; ++r)
          s[mt] = fmaf(fmaxf(acc[nt][mt][r] + bv[r], 0.f), wv[r], s[mt]);
      }
    }
#pragma unroll
    for (int mt = 0; mt < 4; ++mt) {
      s[mt] += __shfl_xor(s[mt], 16, 64);
      s[mt] += __shfl_xor(s[mt], 32, 64);
    }
    if (g == 0) {
#pragma unroll
      for (int mt = 0; mt < 4; ++mt)
        atomicAdd(&predpart[c + 16 * mt], s[mt]);
    }
  }
  __syncthreads();

  if (tid < MT) {
    const float pr = predpart[tid] + bout[node] + 0.5f;
    atomicAdd(&accum[p0 + tid], wgt[tid] * pr);
  }
}

// ---------------------------------------------------------------------------
__global__ void finalize(const float* __restrict__ accum, float* __restrict__ out) {
  const int i = blockIdx.x * 256 + threadIdx.x;
  const float v = accum[i];
  out[i] = v;
  const float zz = 100.0f * (-0.07f - v);
  out[B_ * P_ + i] = 1.0f / (1.0f + expf(-zz));
}

// ---------------------------------------------------------------------------
extern "C" void kernel_launch(void* const* d_in, const int* in_sizes, int n_in,
                              void* d_out, int out_size, void* d_ws, size_t ws_size,
                              hipStream_t stream) {
  const float* X = (const float*)d_in[0];
  const float* latents = (const float*)d_in[1];
  const float* constants = (const float*)d_in[2];
  const float* scales = (const float*)d_in[3];
  const float* rotations = (const float*)d_in[4];
  const float* centers = (const float*)d_in[5];
  const float* W0 = (const float*)d_in[6];
  const float* b0 = (const float*)d_in[7];
  const float* W1 = (const float*)d_in[8];
  const float* b1 = (const float*)d_in[9];
  const float* W2 = (const float*)d_in[10];
  const float* b2 = (const float*)d_in[11];
  const float* Wout = (const float*)d_in[12];
  const float* bout = (const float*)d_in[13];
  const int* use_constants = (const int*)d_in[14];

  float* accum = (float*)d_ws;                       // 8192 f32
  float* Zbuf = accum + B_ * P_;                     // 65536 f32 (contiguous after accum)
  _Float16* WThi = (_Float16*)(Zbuf + B_ * N_ * H_); // 2*32*65536 halves (8 MB)
  _Float16* WTlo = WThi + (size_t)2 * N_ * H_ * H_;  // 8 MB

  // zero accum + Zbuf in one shot (Z is accumulated with atomics now)
  hipMemsetAsync(accum, 0, (B_ * P_ + B_ * N_ * H_) * sizeof(float), stream);

  z_precompute<<<dim3(B_, N_, 4), 256, 0, stream>>>(latents, W0, b0, Zbuf);
  wsplit<<<dim3(N_, 2, 4), 256, 0, stream>>>(W1, W2, WThi, WTlo);

  mlp_main<<<dim3(B_ * P_ / MT * N_), 512, 0, stream>>>(
      X, constants, scales, rotations, centers, W0, b1, b2, Wout, bout,
      Zbuf, WThi, WTlo, use_constants, accum);

  finalize<<<dim3(B_ * P_ / 256), 256, 0, stream>>>(accum, (float*)d_out);
}